// Round 2
// baseline (755.649 us; speedup 1.0000x reference)
//
#include <hip/hip_runtime.h>

#define DIM 512
#define N_ITERS 10

// consts[0]=a=exp(alpha), consts[1]=b=exp(beta), consts[2]=1/(4*s*s)
__global__ void consts_kernel(const float* alpha, const float* beta,
                              const float* sigma, float* consts) {
    if (threadIdx.x == 0 && blockIdx.x == 0) {
        float a = expf(alpha[0]);
        float b = expf(beta[0]);
        float s = expf(sigma[0]);
        consts[0] = a;
        consts[1] = b;
        consts[2] = 1.0f / (4.0f * s * s);
    }
}

// one wave per row: inv_norm[row] = rsqrt(max(sum x^2, 1e-12)); zero normalize
__global__ void rownorm_kernel(const float* __restrict__ x,
                               float* __restrict__ inv_norm,
                               float* __restrict__ normalize, int n) {
    int wid = (blockIdx.x * blockDim.x + threadIdx.x) >> 6;
    int lane = threadIdx.x & 63;
    if (wid >= n) return;
    const float4* p = (const float4*)(x + (size_t)wid * DIM) + lane * 2;
    float4 u = p[0];
    float4 v = p[1];
    float s = u.x*u.x + u.y*u.y + u.z*u.z + u.w*u.w
            + v.x*v.x + v.y*v.y + v.z*v.z + v.w*v.w;
    #pragma unroll
    for (int m = 32; m >= 1; m >>= 1) s += __shfl_xor(s, m, 64);
    if (lane == 0) {
        inv_norm[wid] = rsqrtf(fmaxf(s, 1e-12f));
        normalize[wid] = 0.0f;
    }
}

__device__ __forceinline__ int lower_bound(const int* __restrict__ arr, int n, int key) {
    int lo = 0, hi = n;
    while (lo < hi) {
        int mid = (lo + hi) >> 1;
        if (arr[mid] < key) lo = mid + 1; else hi = mid;
    }
    return lo;
}

__global__ void rowptr_kernel(const int* __restrict__ erow, int nnz,
                              int* __restrict__ rstart, int* __restrict__ rend, int n) {
    int r = blockIdx.x * blockDim.x + threadIdx.x;
    if (r >= n) return;
    rstart[r] = lower_bound(erow, nnz, r);
    rend[r]   = lower_bound(erow, nnz, r + 1);
}

// one wave per edge: sup[e] = edge_val*exp(sim/(4s^2)); atomicAdd normalize[row]
__global__ void edge_kernel(const float* __restrict__ x,
                            const float* __restrict__ inv_norm,
                            const float* __restrict__ eval_,
                            const int* __restrict__ erow, const int* __restrict__ ecol,
                            const float* __restrict__ consts,
                            float* __restrict__ sup, float* __restrict__ normalize, int nnz) {
    int wid = (blockIdx.x * blockDim.x + threadIdx.x) >> 6;
    int lane = threadIdx.x & 63;
    if (wid >= nnz) return;
    int r = erow[wid];
    int c = ecol[wid];
    const float4* pr = (const float4*)(x + (size_t)r * DIM) + lane * 2;
    const float4* pc = (const float4*)(x + (size_t)c * DIM) + lane * 2;
    float4 a0 = pr[0], a1 = pr[1];
    float4 b0 = pc[0], b1 = pc[1];
    float s = a0.x*b0.x + a0.y*b0.y + a0.z*b0.z + a0.w*b0.w
            + a1.x*b1.x + a1.y*b1.y + a1.z*b1.z + a1.w*b1.w;
    #pragma unroll
    for (int m = 32; m >= 1; m >>= 1) s += __shfl_xor(s, m, 64);
    if (lane == 0) {
        float sim = (r == c) ? 0.0f : s * inv_norm[r] * inv_norm[c];
        float e = expf(sim * consts[2]);
        float sp = eval_[wid] * e;
        sup[wid] = sp;
        atomicAdd(normalize + r, sp);
    }
}

__global__ void denom_kernel(const float* __restrict__ normalize,
                             const float* __restrict__ consts,
                             float* __restrict__ inv_denom, int n) {
    int i = blockIdx.x * blockDim.x + threadIdx.x;
    if (i >= n) return;
    float a = consts[0], b = consts[1];
    inv_denom[i] = 1.0f / (b + normalize[i] * a + a);
}

// one block (128 threads) per row; thread t owns cols 4t..4t+3
__global__ void __launch_bounds__(128)
iter_kernel(const float* __restrict__ prev, float* __restrict__ next,
            const float* __restrict__ consts, const float* __restrict__ inv_denom,
            const float* __restrict__ sup, const int* __restrict__ ecol,
            const int* __restrict__ rstart, const int* __restrict__ rend,
            const float* __restrict__ x) {
    int row = blockIdx.x;
    int t = threadIdx.x;
    float a = consts[0], b = consts[1];
    int rs = rstart[row], re = rend[row];
    const size_t base = (size_t)row * DIM;
    float4 acc = make_float4(0.f, 0.f, 0.f, 0.f);
    for (int e = rs; e < re; ++e) {
        float w = sup[e];
        int c = ecol[e];
        float4 v = ((const float4*)(prev + (size_t)c * DIM))[t];
        acc.x += w * v.x; acc.y += w * v.y; acc.z += w * v.z; acc.w += w * v.w;
    }
    float4 self = ((const float4*)(prev + base))[t];
    float4 xv = ((const float4*)(x + base))[t];
    float inv_d = inv_denom[row];
    float4 r;
    r.x = (xv.x * b + (acc.x + self.x) * a) * inv_d;
    r.y = (xv.y * b + (acc.y + self.y) * a) * inv_d;
    r.z = (xv.z * b + (acc.z + self.z) * a) * inv_d;
    r.w = (xv.w * b + (acc.w + self.w) * a) * inv_d;
    ((float4*)(next + base))[t] = r;
}

extern "C" void kernel_launch(void* const* d_in, const int* in_sizes, int n_in,
                              void* d_out, int out_size, void* d_ws, size_t ws_size,
                              hipStream_t stream) {
    const float* x     = (const float*)d_in[0];
    const float* alpha = (const float*)d_in[1];
    const float* beta  = (const float*)d_in[2];
    const float* sigma = (const float*)d_in[3];
    const float* eval_ = (const float*)d_in[4];
    const int* erow = (const int*)d_in[5];
    const int* ecol = (const int*)d_in[6];

    const int n   = in_sizes[0] / DIM;   // 16384
    const int nnz = in_sizes[4];         // 163840

    float* ws        = (float*)d_ws;
    float* consts    = ws;                        // 64 floats (padded)
    float* inv_norm  = ws + 64;                   // n
    float* normalize = inv_norm + n;              // n
    float* inv_denom = normalize + n;             // n
    int*   rstart    = (int*)(inv_denom + n);     // n
    int*   rend      = rstart + n;                // n
    float* sup       = (float*)(rend + n);        // nnz
    float* bufA      = sup + nnz;                 // n*DIM fp32 (~32 MB)
    float* out       = (float*)d_out;             // n*DIM fp32, doubles as ping-pong buf

    consts_kernel<<<1, 64, 0, stream>>>(alpha, beta, sigma, consts);
    rownorm_kernel<<<(n * 64) / 256, 256, 0, stream>>>(x, inv_norm, normalize, n);
    rowptr_kernel<<<(n + 255) / 256, 256, 0, stream>>>(erow, nnz, rstart, rend, n);
    edge_kernel<<<(nnz * 64) / 256, 256, 0, stream>>>(x, inv_norm, eval_, erow, ecol,
                                                      consts, sup, normalize, nnz);
    denom_kernel<<<(n + 255) / 256, 256, 0, stream>>>(normalize, consts, inv_denom, n);

    // it0: x -> bufA; odd its -> d_out; even its -> bufA. it9 (odd) lands in d_out.
    for (int it = 0; it < N_ITERS; ++it) {
        const float* prev = (it == 0) ? x : ((it & 1) ? bufA : out);
        float* next = (it & 1) ? out : bufA;
        iter_kernel<<<n, 128, 0, stream>>>(prev, next, consts, inv_denom,
                                           sup, ecol, rstart, rend, x);
    }
}

// Round 3
// 489.526 us; speedup vs baseline: 1.5436x; 1.5436x over previous
//
#include <hip/hip_runtime.h>
#include <hip/hip_fp16.h>

#define DIM 512
#define N_ITERS 10

__device__ __forceinline__ unsigned int pack2h(float lo, float hi) {
    __half2 h = __float22half2_rn(make_float2(lo, hi));
    return *reinterpret_cast<unsigned int*>(&h);
}
__device__ __forceinline__ float2 unpack2h(unsigned int u) {
    return __half22float2(*reinterpret_cast<__half2*>(&u));
}

// consts[0]=a=exp(alpha), consts[1]=b=exp(beta), consts[2]=1/(4*s*s)
__global__ void consts_kernel(const float* alpha, const float* beta,
                              const float* sigma, float* consts) {
    if (threadIdx.x == 0 && blockIdx.x == 0) {
        float a = expf(alpha[0]);
        float b = expf(beta[0]);
        float s = expf(sigma[0]);
        consts[0] = a;
        consts[1] = b;
        consts[2] = 1.0f / (4.0f * s * s);
    }
}

// one wave per row: inv_norm; xh = fp16(x); xbh = fp16(x*b)
__global__ void __launch_bounds__(256)
rownorm_kernel(const float* __restrict__ x,
               const float* __restrict__ consts,
               float* __restrict__ inv_norm,
               unsigned short* __restrict__ xh,
               unsigned short* __restrict__ xbh, int n) {
    int wid = (blockIdx.x * blockDim.x + threadIdx.x) >> 6;
    int lane = threadIdx.x & 63;
    if (wid >= n) return;
    const size_t base = (size_t)wid * DIM + lane * 8;
    const float4* p = (const float4*)(x + base);
    float4 u = p[0];
    float4 v = p[1];
    float s = u.x*u.x + u.y*u.y + u.z*u.z + u.w*u.w
            + v.x*v.x + v.y*v.y + v.z*v.z + v.w*v.w;
    float b = consts[1];
    uint4 h;
    h.x = pack2h(u.x, u.y); h.y = pack2h(u.z, u.w);
    h.z = pack2h(v.x, v.y); h.w = pack2h(v.z, v.w);
    *(uint4*)(xh + base) = h;
    uint4 hb;
    hb.x = pack2h(u.x * b, u.y * b); hb.y = pack2h(u.z * b, u.w * b);
    hb.z = pack2h(v.x * b, v.y * b); hb.w = pack2h(v.z * b, v.w * b);
    *(uint4*)(xbh + base) = hb;
    #pragma unroll
    for (int m = 32; m >= 1; m >>= 1) s += __shfl_xor(s, m, 64);
    if (lane == 0) inv_norm[wid] = rsqrtf(fmaxf(s, 1e-12f));
}

__device__ __forceinline__ int lower_bound(const int* __restrict__ arr, int n, int key) {
    int lo = 0, hi = n;
    while (lo < hi) {
        int mid = (lo + hi) >> 1;
        if (arr[mid] < key) lo = mid + 1; else hi = mid;
    }
    return lo;
}

__global__ void rowptr_kernel(const int* __restrict__ erow, int nnz,
                              int* __restrict__ rstart, int* __restrict__ rend, int n) {
    int r = blockIdx.x * blockDim.x + threadIdx.x;
    if (r >= n) return;
    rstart[r] = lower_bound(erow, nnz, r);
    rend[r]   = lower_bound(erow, nnz, r + 1);
}

// one wave per ROW: keep normalized r-row in registers, loop its edges;
// writes sup[e] and fused inv_denom[row]. No atomics.
__global__ void __launch_bounds__(256)
edge_row_kernel(const float* __restrict__ x,
                const float* __restrict__ inv_norm,
                const float* __restrict__ eval_,
                const int* __restrict__ ecol,
                const int* __restrict__ rstart, const int* __restrict__ rend,
                const float* __restrict__ consts,
                float* __restrict__ sup, float* __restrict__ inv_denom, int n) {
    int row = (blockIdx.x * blockDim.x + threadIdx.x) >> 6;
    int lane = threadIdx.x & 63;
    if (row >= n) return;
    const float4* pr = (const float4*)(x + (size_t)row * DIM) + lane * 2;
    float4 a0 = pr[0], a1 = pr[1];
    float inr = inv_norm[row];
    a0.x *= inr; a0.y *= inr; a0.z *= inr; a0.w *= inr;
    a1.x *= inr; a1.y *= inr; a1.z *= inr; a1.w *= inr;
    float inv4s2 = consts[2];
    int rs = rstart[row], re = rend[row];
    float norm_acc = 0.0f;
    for (int e = rs; e < re; ++e) {
        int c = ecol[e];
        const float4* pc = (const float4*)(x + (size_t)c * DIM) + lane * 2;
        float4 b0 = pc[0], b1 = pc[1];
        float s = a0.x*b0.x + a0.y*b0.y + a0.z*b0.z + a0.w*b0.w
                + a1.x*b1.x + a1.y*b1.y + a1.z*b1.z + a1.w*b1.w;
        #pragma unroll
        for (int m = 32; m >= 1; m >>= 1) s += __shfl_xor(s, m, 64);
        float sim = (row == c) ? 0.0f : s * inv_norm[c];
        float sp = eval_[e] * expf(sim * inv4s2);
        norm_acc += sp;
        if (lane == 0) sup[e] = sp;
    }
    if (lane == 0) {
        float a = consts[0], b = consts[1];
        inv_denom[row] = 1.0f / (b + norm_acc * a + a);
    }
}

// one wave per row; thread t owns cols 8t..8t+7 (fp16 in/out, fp32 math)
__global__ void __launch_bounds__(256)
iter_kernel(const unsigned short* __restrict__ prev,
            unsigned short* __restrict__ next,
            float* __restrict__ out_f32, int last,
            const float* __restrict__ consts, const float* __restrict__ inv_denom,
            const float* __restrict__ sup, const int* __restrict__ ecol,
            const int* __restrict__ rstart, const int* __restrict__ rend,
            const unsigned short* __restrict__ xbh, int n) {
    int row = (blockIdx.x * blockDim.x + threadIdx.x) >> 6;
    int lane = threadIdx.x & 63;
    if (row >= n) return;
    float a = consts[0];
    float inv_d = inv_denom[row];
    int rs = rstart[row], re = rend[row];
    const size_t base = (size_t)row * DIM + lane * 8;
    float acc0 = 0.f, acc1 = 0.f, acc2 = 0.f, acc3 = 0.f;
    float acc4 = 0.f, acc5 = 0.f, acc6 = 0.f, acc7 = 0.f;
    for (int e = rs; e < re; ++e) {
        float w = sup[e];
        int c = ecol[e];
        uint4 h = *(const uint4*)(prev + (size_t)c * DIM + lane * 8);
        float2 f0 = unpack2h(h.x), f1 = unpack2h(h.y);
        float2 f2 = unpack2h(h.z), f3 = unpack2h(h.w);
        acc0 += w * f0.x; acc1 += w * f0.y;
        acc2 += w * f1.x; acc3 += w * f1.y;
        acc4 += w * f2.x; acc5 += w * f2.y;
        acc6 += w * f3.x; acc7 += w * f3.y;
    }
    uint4 hs = *(const uint4*)(prev + base);
    uint4 hx = *(const uint4*)(xbh + base);
    float2 s0 = unpack2h(hs.x), s1 = unpack2h(hs.y);
    float2 s2 = unpack2h(hs.z), s3 = unpack2h(hs.w);
    float2 x0 = unpack2h(hx.x), x1 = unpack2h(hx.y);
    float2 x2 = unpack2h(hx.z), x3 = unpack2h(hx.w);
    float r0 = (x0.x + (acc0 + s0.x) * a) * inv_d;
    float r1 = (x0.y + (acc1 + s0.y) * a) * inv_d;
    float r2 = (x1.x + (acc2 + s1.x) * a) * inv_d;
    float r3 = (x1.y + (acc3 + s1.y) * a) * inv_d;
    float r4 = (x2.x + (acc4 + s2.x) * a) * inv_d;
    float r5 = (x2.y + (acc5 + s2.y) * a) * inv_d;
    float r6 = (x3.x + (acc6 + s3.x) * a) * inv_d;
    float r7 = (x3.y + (acc7 + s3.y) * a) * inv_d;
    if (last) {
        float4* o = (float4*)(out_f32 + base);
        o[0] = make_float4(r0, r1, r2, r3);
        o[1] = make_float4(r4, r5, r6, r7);
    } else {
        uint4 ho;
        ho.x = pack2h(r0, r1); ho.y = pack2h(r2, r3);
        ho.z = pack2h(r4, r5); ho.w = pack2h(r6, r7);
        *(uint4*)(next + base) = ho;
    }
}

extern "C" void kernel_launch(void* const* d_in, const int* in_sizes, int n_in,
                              void* d_out, int out_size, void* d_ws, size_t ws_size,
                              hipStream_t stream) {
    const float* x     = (const float*)d_in[0];
    const float* alpha = (const float*)d_in[1];
    const float* beta  = (const float*)d_in[2];
    const float* sigma = (const float*)d_in[3];
    const float* eval_ = (const float*)d_in[4];
    const int* ecol = (const int*)d_in[6];
    const int* erow = (const int*)d_in[5];

    const int n   = in_sizes[0] / DIM;   // 16384
    const int nnz = in_sizes[4];         // 163840

    float* ws        = (float*)d_ws;
    float* consts    = ws;                          // 64 floats
    float* inv_norm  = ws + 64;                     // n
    float* inv_denom = inv_norm + n;                // n
    int*   rstart    = (int*)(inv_denom + n);       // n
    int*   rend      = rstart + n;                  // n
    float* sup       = (float*)(rend + n);          // nnz
    unsigned short* xbh  = (unsigned short*)(sup + nnz);   // n*DIM fp16 (16 MB)
    unsigned short* bufB = xbh + (size_t)n * DIM;          // n*DIM fp16 (16 MB)
    unsigned short* bufA = (unsigned short*)d_out;         // first 16 MB of d_out
    float* out_f32 = (float*)d_out;

    consts_kernel<<<1, 64, 0, stream>>>(alpha, beta, sigma, consts);
    rownorm_kernel<<<(n * 64) / 256, 256, 0, stream>>>(x, consts, inv_norm, bufA, xbh, n);
    rowptr_kernel<<<(n + 255) / 256, 256, 0, stream>>>(erow, nnz, rstart, rend, n);
    edge_row_kernel<<<(n * 64) / 256, 256, 0, stream>>>(x, inv_norm, eval_, ecol,
                                                        rstart, rend, consts,
                                                        sup, inv_denom, n);

    // it0: A(xh)->B, it1: B->A, ..., it8: A->B, it9: B->d_out (fp32)
    for (int it = 0; it < N_ITERS; ++it) {
        const unsigned short* prev = (it & 1) ? bufB : bufA;
        unsigned short* next       = (it & 1) ? bufA : bufB;
        int last = (it == N_ITERS - 1) ? 1 : 0;
        iter_kernel<<<(n * 64) / 256, 256, 0, stream>>>(prev, next, out_f32, last,
                                                        consts, inv_denom, sup, ecol,
                                                        rstart, rend, xbh, n);
    }
}

// Round 4
// 430.023 us; speedup vs baseline: 1.7572x; 1.1384x over previous
//
#include <hip/hip_runtime.h>
#include <hip/hip_fp16.h>

#define DIM 512
#define N_ITERS 10

__device__ __forceinline__ unsigned int pack2h(float lo, float hi) {
    __half2 h = __float22half2_rn(make_float2(lo, hi));
    return *reinterpret_cast<unsigned int*>(&h);
}
__device__ __forceinline__ float2 unpack2h(unsigned int u) {
    return __half22float2(*reinterpret_cast<__half2*>(&u));
}

// consts[0]=a=exp(alpha), consts[1]=b=exp(beta), consts[2]=1/(4*s*s)
__global__ void consts_kernel(const float* alpha, const float* beta,
                              const float* sigma, float* consts) {
    if (threadIdx.x == 0 && blockIdx.x == 0) {
        float a = expf(alpha[0]);
        float b = expf(beta[0]);
        float s = expf(sigma[0]);
        consts[0] = a;
        consts[1] = b;
        consts[2] = 1.0f / (4.0f * s * s);
    }
}

// one wave per row: xh = fp16(x) (initial iterate), xnh = fp16(x / ||x||)
__global__ void __launch_bounds__(256)
rownorm_kernel(const float* __restrict__ x,
               unsigned short* __restrict__ xh,
               unsigned short* __restrict__ xnh, int n) {
    int wid = (blockIdx.x * blockDim.x + threadIdx.x) >> 6;
    int lane = threadIdx.x & 63;
    if (wid >= n) return;
    const size_t base = (size_t)wid * DIM + lane * 8;
    const float4* p = (const float4*)(x + base);
    float4 u = p[0];
    float4 v = p[1];
    float s = u.x*u.x + u.y*u.y + u.z*u.z + u.w*u.w
            + v.x*v.x + v.y*v.y + v.z*v.z + v.w*v.w;
    uint4 h;
    h.x = pack2h(u.x, u.y); h.y = pack2h(u.z, u.w);
    h.z = pack2h(v.x, v.y); h.w = pack2h(v.z, v.w);
    *(uint4*)(xh + base) = h;
    #pragma unroll
    for (int m = 32; m >= 1; m >>= 1) s += __shfl_xor(s, m, 64);
    float inr = rsqrtf(fmaxf(s, 1e-12f));
    uint4 hn;
    hn.x = pack2h(u.x * inr, u.y * inr); hn.y = pack2h(u.z * inr, u.w * inr);
    hn.z = pack2h(v.x * inr, v.y * inr); hn.w = pack2h(v.z * inr, v.w * inr);
    *(uint4*)(xnh + base) = hn;
}

__device__ __forceinline__ int lower_bound(const int* __restrict__ arr, int n, int key) {
    int lo = 0, hi = n;
    while (lo < hi) {
        int mid = (lo + hi) >> 1;
        if (arr[mid] < key) lo = mid + 1; else hi = mid;
    }
    return lo;
}

__global__ void rowptr_kernel(const int* __restrict__ erow, int nnz,
                              int* __restrict__ rstart, int* __restrict__ rend, int n) {
    int r = blockIdx.x * blockDim.x + threadIdx.x;
    if (r >= n) return;
    rstart[r] = lower_bound(erow, nnz, r);
    rend[r]   = lower_bound(erow, nnz, r + 1);
}

__device__ __forceinline__ float dot8h(float a0, float a1, float a2, float a3,
                                       float a4, float a5, float a6, float a7, uint4 h) {
    float2 f0 = unpack2h(h.x), f1 = unpack2h(h.y);
    float2 f2 = unpack2h(h.z), f3 = unpack2h(h.w);
    return a0*f0.x + a1*f0.y + a2*f1.x + a3*f1.y
         + a4*f2.x + a5*f2.y + a6*f3.x + a7*f3.y;
}

// one wave per ROW over pre-normalized fp16 rows; unroll x2; fused inv_denom
__global__ void __launch_bounds__(256)
edge_row_kernel(const unsigned short* __restrict__ xnh,
                const float* __restrict__ eval_,
                const int* __restrict__ ecol,
                const int* __restrict__ rstart, const int* __restrict__ rend,
                const float* __restrict__ consts,
                float* __restrict__ sup, float* __restrict__ inv_denom, int n) {
    int row = (blockIdx.x * blockDim.x + threadIdx.x) >> 6;
    int lane = threadIdx.x & 63;
    if (row >= n) return;
    uint4 hr = *(const uint4*)(xnh + (size_t)row * DIM + lane * 8);
    float2 r0 = unpack2h(hr.x), r1 = unpack2h(hr.y);
    float2 r2 = unpack2h(hr.z), r3 = unpack2h(hr.w);
    float a0 = r0.x, a1 = r0.y, a2 = r1.x, a3 = r1.y;
    float a4 = r2.x, a5 = r2.y, a6 = r3.x, a7 = r3.y;
    float c2 = consts[2];
    int rs = rstart[row], re = rend[row];
    float norm_acc = 0.0f;
    int e = rs;
    for (; e + 1 < re; e += 2) {
        int c0 = ecol[e], c1 = ecol[e + 1];
        uint4 h0 = *(const uint4*)(xnh + (size_t)c0 * DIM + lane * 8);
        uint4 h1 = *(const uint4*)(xnh + (size_t)c1 * DIM + lane * 8);
        float s0 = dot8h(a0,a1,a2,a3,a4,a5,a6,a7, h0);
        float s1 = dot8h(a0,a1,a2,a3,a4,a5,a6,a7, h1);
        #pragma unroll
        for (int m = 32; m >= 1; m >>= 1) {
            s0 += __shfl_xor(s0, m, 64);
            s1 += __shfl_xor(s1, m, 64);
        }
        float sim0 = (row == c0) ? 0.0f : s0;
        float sim1 = (row == c1) ? 0.0f : s1;
        float sp0 = eval_[e]     * expf(sim0 * c2);
        float sp1 = eval_[e + 1] * expf(sim1 * c2);
        norm_acc += sp0 + sp1;
        if (lane == 0) { sup[e] = sp0; sup[e + 1] = sp1; }
    }
    if (e < re) {
        int c0 = ecol[e];
        uint4 h0 = *(const uint4*)(xnh + (size_t)c0 * DIM + lane * 8);
        float s0 = dot8h(a0,a1,a2,a3,a4,a5,a6,a7, h0);
        #pragma unroll
        for (int m = 32; m >= 1; m >>= 1) s0 += __shfl_xor(s0, m, 64);
        float sim0 = (row == c0) ? 0.0f : s0;
        float sp0 = eval_[e] * expf(sim0 * c2);
        norm_acc += sp0;
        if (lane == 0) sup[e] = sp0;
    }
    if (lane == 0) {
        float a = consts[0], b = consts[1];
        inv_denom[row] = 1.0f / (b + norm_acc * a + a);
    }
}

// xbh = xh * b (fp16 -> fp16), grid-stride over uint4 chunks
__global__ void __launch_bounds__(256)
xb_kernel(const unsigned short* __restrict__ xh,
          const float* __restrict__ consts,
          unsigned short* __restrict__ xbh, int n_chunks) {
    int i = blockIdx.x * blockDim.x + threadIdx.x;
    if (i >= n_chunks) return;
    float b = consts[1];
    uint4 h = ((const uint4*)xh)[i];
    float2 f0 = unpack2h(h.x), f1 = unpack2h(h.y);
    float2 f2 = unpack2h(h.z), f3 = unpack2h(h.w);
    uint4 o;
    o.x = pack2h(f0.x * b, f0.y * b); o.y = pack2h(f1.x * b, f1.y * b);
    o.z = pack2h(f2.x * b, f2.y * b); o.w = pack2h(f3.x * b, f3.y * b);
    ((uint4*)xbh)[i] = o;
}

// one wave per row; lane owns cols 8L..8L+7; gather loop unrolled x4
__global__ void __launch_bounds__(256)
iter_kernel(const unsigned short* __restrict__ prev,
            unsigned short* __restrict__ next,
            float* __restrict__ out_f32, int last,
            const float* __restrict__ consts, const float* __restrict__ inv_denom,
            const float* __restrict__ sup, const int* __restrict__ ecol,
            const int* __restrict__ rstart, const int* __restrict__ rend,
            const unsigned short* __restrict__ xbh, int n) {
    int row = (blockIdx.x * blockDim.x + threadIdx.x) >> 6;
    int lane = threadIdx.x & 63;
    if (row >= n) return;
    float a = consts[0];
    float inv_d = inv_denom[row];
    int rs = rstart[row], re = rend[row];
    const size_t loff = lane * 8;
    const size_t base = (size_t)row * DIM + loff;
    float acc0 = 0.f, acc1 = 0.f, acc2 = 0.f, acc3 = 0.f;
    float acc4 = 0.f, acc5 = 0.f, acc6 = 0.f, acc7 = 0.f;
    int e = rs;
    for (; e + 3 < re; e += 4) {
        int   c0 = ecol[e],   c1 = ecol[e+1], c2 = ecol[e+2], c3 = ecol[e+3];
        float w0 = sup[e],    w1 = sup[e+1],  w2 = sup[e+2],  w3 = sup[e+3];
        uint4 h0 = *(const uint4*)(prev + (size_t)c0 * DIM + loff);
        uint4 h1 = *(const uint4*)(prev + (size_t)c1 * DIM + loff);
        uint4 h2 = *(const uint4*)(prev + (size_t)c2 * DIM + loff);
        uint4 h3 = *(const uint4*)(prev + (size_t)c3 * DIM + loff);
        float2 f;
        f = unpack2h(h0.x); acc0 += w0*f.x; acc1 += w0*f.y;
        f = unpack2h(h0.y); acc2 += w0*f.x; acc3 += w0*f.y;
        f = unpack2h(h0.z); acc4 += w0*f.x; acc5 += w0*f.y;
        f = unpack2h(h0.w); acc6 += w0*f.x; acc7 += w0*f.y;
        f = unpack2h(h1.x); acc0 += w1*f.x; acc1 += w1*f.y;
        f = unpack2h(h1.y); acc2 += w1*f.x; acc3 += w1*f.y;
        f = unpack2h(h1.z); acc4 += w1*f.x; acc5 += w1*f.y;
        f = unpack2h(h1.w); acc6 += w1*f.x; acc7 += w1*f.y;
        f = unpack2h(h2.x); acc0 += w2*f.x; acc1 += w2*f.y;
        f = unpack2h(h2.y); acc2 += w2*f.x; acc3 += w2*f.y;
        f = unpack2h(h2.z); acc4 += w2*f.x; acc5 += w2*f.y;
        f = unpack2h(h2.w); acc6 += w2*f.x; acc7 += w2*f.y;
        f = unpack2h(h3.x); acc0 += w3*f.x; acc1 += w3*f.y;
        f = unpack2h(h3.y); acc2 += w3*f.x; acc3 += w3*f.y;
        f = unpack2h(h3.z); acc4 += w3*f.x; acc5 += w3*f.y;
        f = unpack2h(h3.w); acc6 += w3*f.x; acc7 += w3*f.y;
    }
    for (; e < re; ++e) {
        float w = sup[e];
        int c = ecol[e];
        uint4 h = *(const uint4*)(prev + (size_t)c * DIM + loff);
        float2 f;
        f = unpack2h(h.x); acc0 += w*f.x; acc1 += w*f.y;
        f = unpack2h(h.y); acc2 += w*f.x; acc3 += w*f.y;
        f = unpack2h(h.z); acc4 += w*f.x; acc5 += w*f.y;
        f = unpack2h(h.w); acc6 += w*f.x; acc7 += w*f.y;
    }
    uint4 hs = *(const uint4*)(prev + base);
    uint4 hx = *(const uint4*)(xbh + base);
    float2 s0 = unpack2h(hs.x), s1 = unpack2h(hs.y);
    float2 s2 = unpack2h(hs.z), s3 = unpack2h(hs.w);
    float2 x0 = unpack2h(hx.x), x1 = unpack2h(hx.y);
    float2 x2 = unpack2h(hx.z), x3 = unpack2h(hx.w);
    float r0 = (x0.x + (acc0 + s0.x) * a) * inv_d;
    float r1 = (x0.y + (acc1 + s0.y) * a) * inv_d;
    float r2 = (x1.x + (acc2 + s1.x) * a) * inv_d;
    float r3 = (x1.y + (acc3 + s1.y) * a) * inv_d;
    float r4 = (x2.x + (acc4 + s2.x) * a) * inv_d;
    float r5 = (x2.y + (acc5 + s2.y) * a) * inv_d;
    float r6 = (x3.x + (acc6 + s3.x) * a) * inv_d;
    float r7 = (x3.y + (acc7 + s3.y) * a) * inv_d;
    if (last) {
        float4* o = (float4*)(out_f32 + base);
        o[0] = make_float4(r0, r1, r2, r3);
        o[1] = make_float4(r4, r5, r6, r7);
    } else {
        uint4 ho;
        ho.x = pack2h(r0, r1); ho.y = pack2h(r2, r3);
        ho.z = pack2h(r4, r5); ho.w = pack2h(r6, r7);
        *(uint4*)(next + base) = ho;
    }
}

extern "C" void kernel_launch(void* const* d_in, const int* in_sizes, int n_in,
                              void* d_out, int out_size, void* d_ws, size_t ws_size,
                              hipStream_t stream) {
    const float* x     = (const float*)d_in[0];
    const float* alpha = (const float*)d_in[1];
    const float* beta  = (const float*)d_in[2];
    const float* sigma = (const float*)d_in[3];
    const float* eval_ = (const float*)d_in[4];
    const int* erow = (const int*)d_in[5];
    const int* ecol = (const int*)d_in[6];

    const int n   = in_sizes[0] / DIM;   // 16384
    const int nnz = in_sizes[4];         // 163840

    float* ws        = (float*)d_ws;
    float* consts    = ws;                          // 64 floats
    float* inv_denom = ws + 64;                     // n
    int*   rstart    = (int*)(inv_denom + n);       // n
    int*   rend      = rstart + n;                  // n
    float* sup       = (float*)(rend + n);          // nnz
    unsigned short* R    = (unsigned short*)(sup + nnz);   // n*DIM fp16 (xnh, then xbh)
    unsigned short* bufB = R + (size_t)n * DIM;            // n*DIM fp16
    unsigned short* bufA = (unsigned short*)d_out;         // first 16 MB of d_out
    float* out_f32 = (float*)d_out;

    consts_kernel<<<1, 64, 0, stream>>>(alpha, beta, sigma, consts);
    rownorm_kernel<<<(n * 64) / 256, 256, 0, stream>>>(x, bufA, R, n);
    rowptr_kernel<<<(n + 255) / 256, 256, 0, stream>>>(erow, nnz, rstart, rend, n);
    edge_row_kernel<<<(n * 64) / 256, 256, 0, stream>>>(R, eval_, ecol,
                                                        rstart, rend, consts,
                                                        sup, inv_denom, n);
    // R is dead as xnh now; reuse it for xbh = xh * b
    int n_chunks = n * DIM / 8;
    xb_kernel<<<(n_chunks + 255) / 256, 256, 0, stream>>>(bufA, consts, R, n_chunks);

    // it0: A(xh)->B, it1: B->A, ..., it8: A->B, it9: B->d_out (fp32)
    for (int it = 0; it < N_ITERS; ++it) {
        const unsigned short* prev = (it & 1) ? bufB : bufA;
        unsigned short* next       = (it & 1) ? bufA : bufB;
        int last = (it == N_ITERS - 1) ? 1 : 0;
        iter_kernel<<<(n * 64) / 256, 256, 0, stream>>>(prev, next, out_f32, last,
                                                        consts, inv_denom, sup, ecol,
                                                        rstart, rend, R, n);
    }
}

// Round 5
// 419.915 us; speedup vs baseline: 1.7995x; 1.0241x over previous
//
#include <hip/hip_runtime.h>
#include <hip/hip_fp16.h>

#define DIM 512
#define N_ITERS 10

__device__ __forceinline__ unsigned int pack2h(float lo, float hi) {
    __half2 h = __float22half2_rn(make_float2(lo, hi));
    return *reinterpret_cast<unsigned int*>(&h);
}
__device__ __forceinline__ float2 unpack2h(unsigned int u) {
    return __half22float2(*reinterpret_cast<__half2*>(&u));
}

// consts[0]=a=exp(alpha), consts[1]=b=exp(beta), consts[2]=1/(4*s*s)
__global__ void consts_kernel(const float* alpha, const float* beta,
                              const float* sigma, float* consts) {
    if (threadIdx.x == 0 && blockIdx.x == 0) {
        float a = expf(alpha[0]);
        float b = expf(beta[0]);
        float s = expf(sigma[0]);
        consts[0] = a;
        consts[1] = b;
        consts[2] = 1.0f / (4.0f * s * s);
    }
}

// one wave per row: xh=fp16(x), xnh=fp16(x/||x||), xbh=fp16(x*b)
__global__ void __launch_bounds__(256)
rownorm_kernel(const float* __restrict__ x,
               const float* __restrict__ consts,
               unsigned short* __restrict__ xh,
               unsigned short* __restrict__ xnh,
               unsigned short* __restrict__ xbh, int n) {
    int wid = (blockIdx.x * blockDim.x + threadIdx.x) >> 6;
    int lane = threadIdx.x & 63;
    if (wid >= n) return;
    const size_t base = (size_t)wid * DIM + lane * 8;
    const float4* p = (const float4*)(x + base);
    float4 u = p[0];
    float4 v = p[1];
    float s = u.x*u.x + u.y*u.y + u.z*u.z + u.w*u.w
            + v.x*v.x + v.y*v.y + v.z*v.z + v.w*v.w;
    uint4 h;
    h.x = pack2h(u.x, u.y); h.y = pack2h(u.z, u.w);
    h.z = pack2h(v.x, v.y); h.w = pack2h(v.z, v.w);
    *(uint4*)(xh + base) = h;
    float b = consts[1];
    uint4 hb;
    hb.x = pack2h(u.x * b, u.y * b); hb.y = pack2h(u.z * b, u.w * b);
    hb.z = pack2h(v.x * b, v.y * b); hb.w = pack2h(v.z * b, v.w * b);
    *(uint4*)(xbh + base) = hb;
    #pragma unroll
    for (int m = 32; m >= 1; m >>= 1) s += __shfl_xor(s, m, 64);
    float inr = rsqrtf(fmaxf(s, 1e-12f));
    uint4 hn;
    hn.x = pack2h(u.x * inr, u.y * inr); hn.y = pack2h(u.z * inr, u.w * inr);
    hn.z = pack2h(v.x * inr, v.y * inr); hn.w = pack2h(v.z * inr, v.w * inr);
    *(uint4*)(xnh + base) = hn;
}

// rstart[r] for r in [0, n]; rend[r] == rstart[r+1]
__global__ void rowptr_kernel(const int* __restrict__ erow, int nnz,
                              int* __restrict__ rstart, int n) {
    int r = blockIdx.x * blockDim.x + threadIdx.x;
    if (r > n) return;
    int lo = 0, hi = nnz;
    while (lo < hi) {
        int mid = (lo + hi) >> 1;
        if (erow[mid] < r) lo = mid + 1; else hi = mid;
    }
    rstart[r] = lo;
}

__device__ __forceinline__ float dot8h(float a0, float a1, float a2, float a3,
                                       float a4, float a5, float a6, float a7, uint4 h) {
    float2 f0 = unpack2h(h.x), f1 = unpack2h(h.y);
    float2 f2 = unpack2h(h.z), f3 = unpack2h(h.w);
    return a0*f0.x + a1*f0.y + a2*f1.x + a3*f1.y
         + a4*f2.x + a5*f2.y + a6*f3.x + a7*f3.y;
}

// one wave per ROW over pre-normalized fp16 rows; 4-deep pipeline; fused inv_denom
__global__ void __launch_bounds__(256)
edge_row_kernel(const unsigned short* __restrict__ xnh,
                const float* __restrict__ eval_,
                const int* __restrict__ ecol,
                const int* __restrict__ rstart,
                const float* __restrict__ consts,
                float* __restrict__ sup, float* __restrict__ inv_denom, int n) {
    int row = (blockIdx.x * blockDim.x + threadIdx.x) >> 6;
    int lane = threadIdx.x & 63;
    if (row >= n) return;
    uint4 hr = *(const uint4*)(xnh + (size_t)row * DIM + lane * 8);
    float2 r0 = unpack2h(hr.x), r1 = unpack2h(hr.y);
    float2 r2 = unpack2h(hr.z), r3 = unpack2h(hr.w);
    float a0 = r0.x, a1 = r0.y, a2 = r1.x, a3 = r1.y;
    float a4 = r2.x, a5 = r2.y, a6 = r3.x, a7 = r3.y;
    float c2 = consts[2];
    int rs = rstart[row], re = rstart[row + 1];
    float norm_acc = 0.0f;
    int e = rs;
    for (; e + 3 < re; e += 4) {
        int c[4]; uint4 h[4]; float s[4];
        #pragma unroll
        for (int j = 0; j < 4; ++j) c[j] = ecol[e + j];
        #pragma unroll
        for (int j = 0; j < 4; ++j)
            h[j] = *(const uint4*)(xnh + (size_t)c[j] * DIM + lane * 8);
        #pragma unroll
        for (int j = 0; j < 4; ++j)
            s[j] = dot8h(a0,a1,a2,a3,a4,a5,a6,a7, h[j]);
        #pragma unroll
        for (int m = 32; m >= 1; m >>= 1) {
            #pragma unroll
            for (int j = 0; j < 4; ++j) s[j] += __shfl_xor(s[j], m, 64);
        }
        #pragma unroll
        for (int j = 0; j < 4; ++j) {
            float sim = (row == c[j]) ? 0.0f : s[j];
            float sp = eval_[e + j] * expf(sim * c2);
            norm_acc += sp;
            if (lane == 0) sup[e + j] = sp;
        }
    }
    for (; e < re; ++e) {
        int c0 = ecol[e];
        uint4 h0 = *(const uint4*)(xnh + (size_t)c0 * DIM + lane * 8);
        float s0 = dot8h(a0,a1,a2,a3,a4,a5,a6,a7, h0);
        #pragma unroll
        for (int m = 32; m >= 1; m >>= 1) s0 += __shfl_xor(s0, m, 64);
        float sim0 = (row == c0) ? 0.0f : s0;
        float sp0 = eval_[e] * expf(sim0 * c2);
        norm_acc += sp0;
        if (lane == 0) sup[e] = sp0;
    }
    if (lane == 0) {
        float a = consts[0], b = consts[1];
        inv_denom[row] = 1.0f / (b + norm_acc * a + a);
    }
}

#define ACC8(hh, ww)                                          \
    do {                                                      \
        float2 f_;                                            \
        f_ = unpack2h((hh).x); acc0 += (ww)*f_.x; acc1 += (ww)*f_.y; \
        f_ = unpack2h((hh).y); acc2 += (ww)*f_.x; acc3 += (ww)*f_.y; \
        f_ = unpack2h((hh).z); acc4 += (ww)*f_.x; acc5 += (ww)*f_.y; \
        f_ = unpack2h((hh).w); acc6 += (ww)*f_.x; acc7 += (ww)*f_.y; \
    } while (0)

// one wave per row; lane owns cols 8L..8L+7; 8-deep gather pipeline
__global__ void __launch_bounds__(256)
iter_kernel(const unsigned short* __restrict__ prev,
            unsigned short* __restrict__ next,
            float* __restrict__ out_f32, int last,
            const float* __restrict__ consts, const float* __restrict__ inv_denom,
            const float* __restrict__ sup, const int* __restrict__ ecol,
            const int* __restrict__ rstart,
            const unsigned short* __restrict__ xbh, int n) {
    int row = (blockIdx.x * blockDim.x + threadIdx.x) >> 6;
    int lane = threadIdx.x & 63;
    if (row >= n) return;
    float a = consts[0];
    float inv_d = inv_denom[row];
    int rs = rstart[row], re = rstart[row + 1];
    const size_t loff = lane * 8;
    const size_t base = (size_t)row * DIM + loff;
    float acc0 = 0.f, acc1 = 0.f, acc2 = 0.f, acc3 = 0.f;
    float acc4 = 0.f, acc5 = 0.f, acc6 = 0.f, acc7 = 0.f;
    int e = rs;
    for (; e + 7 < re; e += 8) {
        int c[8]; float w[8]; uint4 h[8];
        #pragma unroll
        for (int j = 0; j < 8; ++j) { c[j] = ecol[e + j]; w[j] = sup[e + j]; }
        #pragma unroll
        for (int j = 0; j < 8; ++j)
            h[j] = *(const uint4*)(prev + (size_t)c[j] * DIM + loff);
        #pragma unroll
        for (int j = 0; j < 8; ++j) ACC8(h[j], w[j]);
    }
    for (; e + 1 < re; e += 2) {
        int c0 = ecol[e], c1 = ecol[e + 1];
        float w0 = sup[e], w1 = sup[e + 1];
        uint4 h0 = *(const uint4*)(prev + (size_t)c0 * DIM + loff);
        uint4 h1 = *(const uint4*)(prev + (size_t)c1 * DIM + loff);
        ACC8(h0, w0);
        ACC8(h1, w1);
    }
    if (e < re) {
        float w = sup[e];
        int c = ecol[e];
        uint4 h = *(const uint4*)(prev + (size_t)c * DIM + loff);
        ACC8(h, w);
    }
    uint4 hs = *(const uint4*)(prev + base);
    uint4 hx = *(const uint4*)(xbh + base);
    float2 s0 = unpack2h(hs.x), s1 = unpack2h(hs.y);
    float2 s2 = unpack2h(hs.z), s3 = unpack2h(hs.w);
    float2 x0 = unpack2h(hx.x), x1 = unpack2h(hx.y);
    float2 x2 = unpack2h(hx.z), x3 = unpack2h(hx.w);
    float r0 = (x0.x + (acc0 + s0.x) * a) * inv_d;
    float r1 = (x0.y + (acc1 + s0.y) * a) * inv_d;
    float r2 = (x1.x + (acc2 + s1.x) * a) * inv_d;
    float r3 = (x1.y + (acc3 + s1.y) * a) * inv_d;
    float r4 = (x2.x + (acc4 + s2.x) * a) * inv_d;
    float r5 = (x2.y + (acc5 + s2.y) * a) * inv_d;
    float r6 = (x3.x + (acc6 + s3.x) * a) * inv_d;
    float r7 = (x3.y + (acc7 + s3.y) * a) * inv_d;
    if (last) {
        float4* o = (float4*)(out_f32 + base);
        o[0] = make_float4(r0, r1, r2, r3);
        o[1] = make_float4(r4, r5, r6, r7);
    } else {
        uint4 ho;
        ho.x = pack2h(r0, r1); ho.y = pack2h(r2, r3);
        ho.z = pack2h(r4, r5); ho.w = pack2h(r6, r7);
        *(uint4*)(next + base) = ho;
    }
}

extern "C" void kernel_launch(void* const* d_in, const int* in_sizes, int n_in,
                              void* d_out, int out_size, void* d_ws, size_t ws_size,
                              hipStream_t stream) {
    const float* x     = (const float*)d_in[0];
    const float* alpha = (const float*)d_in[1];
    const float* beta  = (const float*)d_in[2];
    const float* sigma = (const float*)d_in[3];
    const float* eval_ = (const float*)d_in[4];
    const int* erow = (const int*)d_in[5];
    const int* ecol = (const int*)d_in[6];

    const int n   = in_sizes[0] / DIM;   // 16384
    const int nnz = in_sizes[4];         // 163840

    float* ws        = (float*)d_ws;
    float* consts    = ws;                          // 64 floats
    float* inv_denom = ws + 64;                     // n
    int*   rstart    = (int*)(inv_denom + n);       // n+1
    float* sup       = (float*)(rstart + n + 64);   // nnz
    unsigned short* xnh  = (unsigned short*)(sup + nnz);   // n*DIM fp16 (16 MB)
    unsigned short* xbh  = xnh + (size_t)n * DIM;          // n*DIM fp16 (16 MB)
    unsigned short* bufB = xbh + (size_t)n * DIM;          // n*DIM fp16 (16 MB)
    unsigned short* bufA = (unsigned short*)d_out;         // first 16 MB of d_out
    float* out_f32 = (float*)d_out;

    consts_kernel<<<1, 64, 0, stream>>>(alpha, beta, sigma, consts);
    rownorm_kernel<<<(n * 64) / 256, 256, 0, stream>>>(x, consts, bufA, xnh, xbh, n);
    rowptr_kernel<<<(n + 256) / 256, 256, 0, stream>>>(erow, nnz, rstart, n);
    edge_row_kernel<<<(n * 64) / 256, 256, 0, stream>>>(xnh, eval_, ecol,
                                                        rstart, consts,
                                                        sup, inv_denom, n);

    // it0: A(xh)->B, it1: B->A, ..., it8: A->B, it9: B->d_out (fp32)
    for (int it = 0; it < N_ITERS; ++it) {
        const unsigned short* prev = (it & 1) ? bufB : bufA;
        unsigned short* next       = (it & 1) ? bufA : bufB;
        int last = (it == N_ITERS - 1) ? 1 : 0;
        iter_kernel<<<(n * 64) / 256, 256, 0, stream>>>(prev, next, out_f32, last,
                                                        consts, inv_denom, sup, ecol,
                                                        rstart, xbh, n);
    }
}

// Round 6
// 333.438 us; speedup vs baseline: 2.2662x; 1.2594x over previous
//
#include <hip/hip_runtime.h>
#include <hip/hip_fp16.h>

#define DIM 512
#define N_ITERS 10

typedef float floatx2 __attribute__((ext_vector_type(2)));

__device__ __forceinline__ unsigned int pack2h(float lo, float hi) {
    __half2 h = __float22half2_rn(make_float2(lo, hi));
    return *reinterpret_cast<unsigned int*>(&h);
}
__device__ __forceinline__ float2 unpack2h(unsigned int u) {
    return __half22float2(*reinterpret_cast<__half2*>(&u));
}
// pack 4 floats -> 4 fp8 e4m3 in one uint (f0,f1 -> word0; f2,f3 -> word1)
__device__ __forceinline__ unsigned int pack4f8(float f0, float f1, float f2, float f3) {
    int v = 0;
    v = __builtin_amdgcn_cvt_pk_fp8_f32(f0, f1, v, false);
    v = __builtin_amdgcn_cvt_pk_fp8_f32(f2, f3, v, true);
    return (unsigned int)v;
}

// consts[0]=a=exp(alpha), consts[1]=b=exp(beta), consts[2]=1/(4*s*s)
__global__ void consts_kernel(const float* alpha, const float* beta,
                              const float* sigma, float* consts) {
    if (threadIdx.x == 0 && blockIdx.x == 0) {
        float a = expf(alpha[0]);
        float b = expf(beta[0]);
        float s = expf(sigma[0]);
        consts[0] = a;
        consts[1] = b;
        consts[2] = 1.0f / (4.0f * s * s);
    }
}

// one wave per row: xh16=fp16(x), x8=fp8(x), xn8=fp8(x/||x||), xbh=fp16(x*b)
__global__ void __launch_bounds__(256)
rownorm_kernel(const float* __restrict__ x,
               const float* __restrict__ consts,
               unsigned short* __restrict__ xh16,
               unsigned int* __restrict__ x8,      // uint-per-4, row stride DIM/4
               unsigned int* __restrict__ xn8,
               unsigned short* __restrict__ xbh, int n) {
    int wid = (blockIdx.x * blockDim.x + threadIdx.x) >> 6;
    int lane = threadIdx.x & 63;
    if (wid >= n) return;
    const size_t base = (size_t)wid * DIM + lane * 8;
    const float4* p = (const float4*)(x + base);
    float4 u = p[0];
    float4 v = p[1];
    float s = u.x*u.x + u.y*u.y + u.z*u.z + u.w*u.w
            + v.x*v.x + v.y*v.y + v.z*v.z + v.w*v.w;
    uint4 h;
    h.x = pack2h(u.x, u.y); h.y = pack2h(u.z, u.w);
    h.z = pack2h(v.x, v.y); h.w = pack2h(v.z, v.w);
    *(uint4*)(xh16 + base) = h;
    uint2 q;
    q.x = pack4f8(u.x, u.y, u.z, u.w);
    q.y = pack4f8(v.x, v.y, v.z, v.w);
    *(uint2*)(x8 + ((size_t)wid * (DIM / 4) + lane * 2)) = q;
    float b = consts[1];
    uint4 hb;
    hb.x = pack2h(u.x * b, u.y * b); hb.y = pack2h(u.z * b, u.w * b);
    hb.z = pack2h(v.x * b, v.y * b); hb.w = pack2h(v.z * b, v.w * b);
    *(uint4*)(xbh + base) = hb;
    #pragma unroll
    for (int m = 32; m >= 1; m >>= 1) s += __shfl_xor(s, m, 64);
    float inr = rsqrtf(fmaxf(s, 1e-12f));
    uint2 qn;
    qn.x = pack4f8(u.x * inr, u.y * inr, u.z * inr, u.w * inr);
    qn.y = pack4f8(v.x * inr, v.y * inr, v.z * inr, v.w * inr);
    *(uint2*)(xn8 + ((size_t)wid * (DIM / 4) + lane * 2)) = qn;
}

// rstart[r] for r in [0, n]
__global__ void rowptr_kernel(const int* __restrict__ erow, int nnz,
                              int* __restrict__ rstart, int n) {
    int r = blockIdx.x * blockDim.x + threadIdx.x;
    if (r > n) return;
    int lo = 0, hi = nnz;
    while (lo < hi) {
        int mid = (lo + hi) >> 1;
        if (erow[mid] < r) lo = mid + 1; else hi = mid;
    }
    rstart[r] = lo;
}

__device__ __forceinline__ float dot8f8(const float* A, uint2 h) {
    floatx2 p0 = __builtin_amdgcn_cvt_pk_f32_fp8((int)h.x, false);
    floatx2 p1 = __builtin_amdgcn_cvt_pk_f32_fp8((int)h.x, true);
    floatx2 p2 = __builtin_amdgcn_cvt_pk_f32_fp8((int)h.y, false);
    floatx2 p3 = __builtin_amdgcn_cvt_pk_f32_fp8((int)h.y, true);
    return A[0]*p0.x + A[1]*p0.y + A[2]*p1.x + A[3]*p1.y
         + A[4]*p2.x + A[5]*p2.y + A[6]*p3.x + A[7]*p3.y;
}

// one wave per ROW over fp8 normalized rows; 4-deep pipeline; fused inv_denom
__global__ void __launch_bounds__(256)
edge_row_kernel(const unsigned int* __restrict__ xn8,
                const float* __restrict__ eval_,
                const int* __restrict__ ecol,
                const int* __restrict__ rstart,
                const float* __restrict__ consts,
                float* __restrict__ sup, float* __restrict__ inv_denom, int n) {
    int row = (blockIdx.x * blockDim.x + threadIdx.x) >> 6;
    int lane = threadIdx.x & 63;
    if (row >= n) return;
    uint2 hr = *(const uint2*)(xn8 + (size_t)row * (DIM / 4) + lane * 2);
    float A[8];
    {
        floatx2 p0 = __builtin_amdgcn_cvt_pk_f32_fp8((int)hr.x, false);
        floatx2 p1 = __builtin_amdgcn_cvt_pk_f32_fp8((int)hr.x, true);
        floatx2 p2 = __builtin_amdgcn_cvt_pk_f32_fp8((int)hr.y, false);
        floatx2 p3 = __builtin_amdgcn_cvt_pk_f32_fp8((int)hr.y, true);
        A[0]=p0.x; A[1]=p0.y; A[2]=p1.x; A[3]=p1.y;
        A[4]=p2.x; A[5]=p2.y; A[6]=p3.x; A[7]=p3.y;
    }
    float c2 = consts[2];
    int rs = rstart[row], re = rstart[row + 1];
    float norm_acc = 0.0f;
    int e = rs;
    for (; e + 3 < re; e += 4) {
        int c[4]; uint2 h[4]; float s[4];
        #pragma unroll
        for (int j = 0; j < 4; ++j) c[j] = ecol[e + j];
        #pragma unroll
        for (int j = 0; j < 4; ++j)
            h[j] = *(const uint2*)(xn8 + (size_t)c[j] * (DIM / 4) + lane * 2);
        #pragma unroll
        for (int j = 0; j < 4; ++j) s[j] = dot8f8(A, h[j]);
        #pragma unroll
        for (int m = 32; m >= 1; m >>= 1) {
            #pragma unroll
            for (int j = 0; j < 4; ++j) s[j] += __shfl_xor(s[j], m, 64);
        }
        #pragma unroll
        for (int j = 0; j < 4; ++j) {
            float sim = (row == c[j]) ? 0.0f : s[j];
            float sp = eval_[e + j] * expf(sim * c2);
            norm_acc += sp;
            if (lane == 0) sup[e + j] = sp;
        }
    }
    for (; e < re; ++e) {
        int c0 = ecol[e];
        uint2 h0 = *(const uint2*)(xn8 + (size_t)c0 * (DIM / 4) + lane * 2);
        float s0 = dot8f8(A, h0);
        #pragma unroll
        for (int m = 32; m >= 1; m >>= 1) s0 += __shfl_xor(s0, m, 64);
        float sim0 = (row == c0) ? 0.0f : s0;
        float sp0 = eval_[e] * expf(sim0 * c2);
        norm_acc += sp0;
        if (lane == 0) sup[e] = sp0;
    }
    if (lane == 0) {
        float a = consts[0], b = consts[1];
        inv_denom[row] = 1.0f / (b + norm_acc * a + a);
    }
}

#define ACCF8(hh, ww)                                                              \
    do {                                                                           \
        floatx2 p_;                                                                \
        p_ = __builtin_amdgcn_cvt_pk_f32_fp8((int)(hh).x, false); acc0 += (ww)*p_.x; acc1 += (ww)*p_.y; \
        p_ = __builtin_amdgcn_cvt_pk_f32_fp8((int)(hh).x, true);  acc2 += (ww)*p_.x; acc3 += (ww)*p_.y; \
        p_ = __builtin_amdgcn_cvt_pk_f32_fp8((int)(hh).y, false); acc4 += (ww)*p_.x; acc5 += (ww)*p_.y; \
        p_ = __builtin_amdgcn_cvt_pk_f32_fp8((int)(hh).y, true);  acc6 += (ww)*p_.x; acc7 += (ww)*p_.y; \
    } while (0)

// one wave per row; lane owns cols 8L..8L+7; gathers fp8, self/epilogue fp16
__global__ void __launch_bounds__(256)
iter_kernel(const unsigned short* __restrict__ prev16,
            const unsigned int* __restrict__ prev8,
            unsigned short* __restrict__ next16,
            unsigned int* __restrict__ next8,
            float* __restrict__ out_f32, int last,
            const float* __restrict__ consts, const float* __restrict__ inv_denom,
            const float* __restrict__ sup, const int* __restrict__ ecol,
            const int* __restrict__ rstart,
            const unsigned short* __restrict__ xbh, int n) {
    int row = (blockIdx.x * blockDim.x + threadIdx.x) >> 6;
    int lane = threadIdx.x & 63;
    if (row >= n) return;
    float a = consts[0];
    float inv_d = inv_denom[row];
    int rs = rstart[row], re = rstart[row + 1];
    const size_t loff16 = lane * 8;
    const size_t base16 = (size_t)row * DIM + loff16;
    const size_t loff8 = lane * 2;
    float acc0 = 0.f, acc1 = 0.f, acc2 = 0.f, acc3 = 0.f;
    float acc4 = 0.f, acc5 = 0.f, acc6 = 0.f, acc7 = 0.f;
    int e = rs;
    for (; e + 7 < re; e += 8) {
        int c[8]; float w[8]; uint2 h[8];
        #pragma unroll
        for (int j = 0; j < 8; ++j) { c[j] = ecol[e + j]; w[j] = sup[e + j]; }
        #pragma unroll
        for (int j = 0; j < 8; ++j)
            h[j] = *(const uint2*)(prev8 + (size_t)c[j] * (DIM / 4) + loff8);
        #pragma unroll
        for (int j = 0; j < 8; ++j) ACCF8(h[j], w[j]);
    }
    for (; e + 1 < re; e += 2) {
        int c0 = ecol[e], c1 = ecol[e + 1];
        float w0 = sup[e], w1 = sup[e + 1];
        uint2 h0 = *(const uint2*)(prev8 + (size_t)c0 * (DIM / 4) + loff8);
        uint2 h1 = *(const uint2*)(prev8 + (size_t)c1 * (DIM / 4) + loff8);
        ACCF8(h0, w0);
        ACCF8(h1, w1);
    }
    if (e < re) {
        float w = sup[e];
        int c = ecol[e];
        uint2 h = *(const uint2*)(prev8 + (size_t)c * (DIM / 4) + loff8);
        ACCF8(h, w);
    }
    uint4 hs = *(const uint4*)(prev16 + base16);
    uint4 hx = *(const uint4*)(xbh + base16);
    float2 s0 = unpack2h(hs.x), s1 = unpack2h(hs.y);
    float2 s2 = unpack2h(hs.z), s3 = unpack2h(hs.w);
    float2 x0 = unpack2h(hx.x), x1 = unpack2h(hx.y);
    float2 x2 = unpack2h(hx.z), x3 = unpack2h(hx.w);
    float r0 = (x0.x + (acc0 + s0.x) * a) * inv_d;
    float r1 = (x0.y + (acc1 + s0.y) * a) * inv_d;
    float r2 = (x1.x + (acc2 + s1.x) * a) * inv_d;
    float r3 = (x1.y + (acc3 + s1.y) * a) * inv_d;
    float r4 = (x2.x + (acc4 + s2.x) * a) * inv_d;
    float r5 = (x2.y + (acc5 + s2.y) * a) * inv_d;
    float r6 = (x3.x + (acc6 + s3.x) * a) * inv_d;
    float r7 = (x3.y + (acc7 + s3.y) * a) * inv_d;
    if (last) {
        float4* o = (float4*)(out_f32 + base16);
        o[0] = make_float4(r0, r1, r2, r3);
        o[1] = make_float4(r4, r5, r6, r7);
    } else {
        uint4 ho;
        ho.x = pack2h(r0, r1); ho.y = pack2h(r2, r3);
        ho.z = pack2h(r4, r5); ho.w = pack2h(r6, r7);
        *(uint4*)(next16 + base16) = ho;
        uint2 q;
        q.x = pack4f8(r0, r1, r2, r3);
        q.y = pack4f8(r4, r5, r6, r7);
        *(uint2*)(next8 + (size_t)row * (DIM / 4) + loff8) = q;
    }
}

extern "C" void kernel_launch(void* const* d_in, const int* in_sizes, int n_in,
                              void* d_out, int out_size, void* d_ws, size_t ws_size,
                              hipStream_t stream) {
    const float* x     = (const float*)d_in[0];
    const float* alpha = (const float*)d_in[1];
    const float* beta  = (const float*)d_in[2];
    const float* sigma = (const float*)d_in[3];
    const float* eval_ = (const float*)d_in[4];
    const int* erow = (const int*)d_in[5];
    const int* ecol = (const int*)d_in[6];

    const int n   = in_sizes[0] / DIM;   // 16384
    const int nnz = in_sizes[4];         // 163840

    float* ws        = (float*)d_ws;
    float* consts    = ws;                            // 64 floats
    float* inv_denom = ws + 64;                       // n
    int*   rstart    = (int*)(inv_denom + n);         // n+1 (+pad)
    float* sup       = (float*)(rstart + n + 64);     // nnz
    unsigned short* xbh   = (unsigned short*)(sup + nnz);       // n*DIM fp16 (16 MB)
    unsigned short* bufB16= xbh + (size_t)n * DIM;              // n*DIM fp16 (16 MB)
    unsigned int*   xn8   = (unsigned int*)(bufB16 + (size_t)n * DIM); // n*DIM/4 uints (8 MB)
    unsigned int*   bufA8 = xn8 + (size_t)n * (DIM / 4);        // 8 MB
    unsigned int*   bufB8 = bufA8 + (size_t)n * (DIM / 4);      // 8 MB
    unsigned short* bufA16 = (unsigned short*)d_out;            // first 16 MB of d_out
    float* out_f32 = (float*)d_out;

    consts_kernel<<<1, 64, 0, stream>>>(alpha, beta, sigma, consts);
    rownorm_kernel<<<(n * 64) / 256, 256, 0, stream>>>(x, consts, bufA16, bufA8, xn8, xbh, n);
    rowptr_kernel<<<(n + 256) / 256, 256, 0, stream>>>(erow, nnz, rstart, n);
    edge_row_kernel<<<(n * 64) / 256, 256, 0, stream>>>(xn8, eval_, ecol,
                                                        rstart, consts,
                                                        sup, inv_denom, n);

    // it even: A->B, it odd: B->A; it9 (odd) reads B, writes fp32 d_out
    for (int it = 0; it < N_ITERS; ++it) {
        const unsigned short* prev16 = (it & 1) ? bufB16 : bufA16;
        const unsigned int*   prev8  = (it & 1) ? bufB8  : bufA8;
        unsigned short* next16 = (it & 1) ? bufA16 : bufB16;
        unsigned int*   next8  = (it & 1) ? bufA8  : bufB8;
        int last = (it == N_ITERS - 1) ? 1 : 0;
        iter_kernel<<<(n * 64) / 256, 256, 0, stream>>>(prev16, prev8, next16, next8,
                                                        out_f32, last,
                                                        consts, inv_denom, sup, ecol,
                                                        rstart, xbh, n);
    }
}